// Round 17
// baseline (117256.433 us; speedup 1.0000x reference)
//
#include <hip/hip_runtime.h>
#include <hip/hip_bf16.h>
#include <cstdint>

// LSTM, T=32768 steps, C=512, I=1024 (x 512 | h 512), fp32.
// R17 = R16 with the publish-address typo fixed (was sc*1024 + b*32 + 2r,
// OOB for b>=32 -> readers starved -> timeout) and a fast-fail guard.
// Design: fused single launch, BARRIER-FREE step loop. Each wave polls the
// tagged h-words its lanes consume directly into registers (16 u64/lane,
// __all-uniform spin) -- no LDS h buffer, no __syncthreads in the loop,
// 4 independent detection paths. x-pipeline in the publish-flight window
// (R15). Protocol: tagged u64 mailbox (tag<<32|bits), relaxed agent store
// publish, relaxed agent loads. Wave-granular slot-reuse induction:
// word overwritten with tag t+3 only after owner's step-t+2 poll saw all
// tag-t+2 words, each published after its wave's step-t+1 poll completed
// -> nobody still reads tag t+1 when it is overwritten.

#define T_TOTAL 32768
#define NBLK 64

__device__ __forceinline__ float sigm(float x) {
    return 1.0f / (1.0f + __expf(-x));
}
__device__ __forceinline__ float tanh_fast(float x) {
    float ax = fabsf(x);
    float e = __expf(2.0f * ax);          // +inf for large ax is fine -> t = 1
    float t = 1.0f - 2.0f / (e + 1.0f);
    return copysignf(t, x);
}

#define FMA4(a, wv, vv) \
    a = fmaf((wv).x, (vv).x, a); a = fmaf((wv).y, (vv).y, a); \
    a = fmaf((wv).z, (vv).z, a); a = fmaf((wv).w, (vv).w, a)

// ---------------------------------------------------------------------------
// 64 blocks x 256 threads, 1 block/CU. Block owns 8 rows; wave w publishes
// rows 2w, 2w+1 (its seg==0 lanes). Thread: r = tid>>5, seg = tid&31
// (thread covers k in {4seg + 128jj + e}, jj,e in 0..3).
// Weight LDS reader-keyed (lane-linear, 0 conflicts, R8-proven):
//   w?lds4[w*1024 + g*256 + jj*64 + lane], base col 0 (Wx) / 512 (Wh).
// Mailbox: hdq[2][64 blk][16], word (blk,rr) = tagged h[blk*8+rr], rr 0..7.
// Per-lane poll set (covers k = 4seg+128jj+e): words at
//   (seg>>1)*16 + 4*(seg&1) + 256*jj + e      [jj,e in 0..3]
// Each 32-lane half covers all 512 words -> __all() spin is full-coverage.
// ---------------------------------------------------------------------------
__global__ __launch_bounds__(256, 1) void lstm_fused(
    const float* __restrict__ x,
    const float* __restrict__ wf, const float* __restrict__ wi,
    const float* __restrict__ wc, const float* __restrict__ wo,
    const float* __restrict__ bf, const float* __restrict__ bi,
    const float* __restrict__ bc, const float* __restrict__ bo,
    unsigned long long* __restrict__ hdq,   // [2][64][16] tagged h lines
    float* __restrict__ out)
{
    __shared__ alignas(16) float4 whlds4[4096];  // Wh slice, 64 KB
    __shared__ alignas(16) float4 wxlds4[4096];  // Wx slice, 64 KB

    const int b   = blockIdx.x;            // 0..63
    const int tid = threadIdx.x;
    const int r   = tid >> 5;              // 0..7 (block-row)
    const int seg = tid & 31;              // 0..31
    const int w   = tid >> 6;              // wave 0..3
    const int l   = tid & 63;              // lane in wave

    // stage Wx AND Wh slices once (8192 float4s)
    #pragma unroll
    for (int k = 0; k < 32; ++k) {
        int idx  = k * 256 + tid;          // 0..8191
        int sel  = idx >> 12;              // 0: Wh, 1: Wx
        int idx2 = idx & 4095;
        int ll   = idx2 & 63;
        int jj   = (idx2 >> 6) & 3;
        int gg   = (idx2 >> 8) & 3;
        int ww   = idx2 >> 10;
        const float* Wp = (gg == 0) ? wf : (gg == 1) ? wi : (gg == 2) ? wc : wo;
        int row  = b * 8 + ww * 2 + (ll >> 5);
        int col  = 4 * (ll & 31) + 128 * jj + (sel ? 0 : 512);
        float4 v = *(const float4*)(Wp + (size_t)row * 1024 + col);
        if (sel) wxlds4[idx2] = v; else whlds4[idx2] = v;
    }
    const int row = b * 8 + r;
    float4 bias4 = make_float4(bf[row], bi[row], bc[row], bo[row]);

    float cold = 0.f;                      // c state in registers all T steps
    __syncthreads();                       // the ONLY barrier (weights ready)

    const int wbase = w * 1024 + l;        // + g*256 + jj*64
    const int lbase = l & 32;              // base lane of this row-group
    const int pbase = ((seg >> 1) << 4) + ((seg & 1) << 2);  // + 256*jj + e

    // ---- x-partials for step 0 (prologue) ----
    float a0, a1, a2, a3;
    {
        const float4* xp = (const float4*)x;
        float4 xv0 = xp[seg], xv1 = xp[seg + 32],
               xv2 = xp[seg + 64], xv3 = xp[seg + 96];
        float4 q0, q1, q2, q3;
        a0 = a1 = a2 = a3 = 0.f;
        q0 = wxlds4[wbase +   0]; q1 = wxlds4[wbase +  64];
        q2 = wxlds4[wbase + 128]; q3 = wxlds4[wbase + 192];
        FMA4(a0, q0, xv0); FMA4(a0, q1, xv1); FMA4(a0, q2, xv2); FMA4(a0, q3, xv3);
        q0 = wxlds4[wbase + 256]; q1 = wxlds4[wbase + 320];
        q2 = wxlds4[wbase + 384]; q3 = wxlds4[wbase + 448];
        FMA4(a1, q0, xv0); FMA4(a1, q1, xv1); FMA4(a1, q2, xv2); FMA4(a1, q3, xv3);
        q0 = wxlds4[wbase + 512]; q1 = wxlds4[wbase + 576];
        q2 = wxlds4[wbase + 640]; q3 = wxlds4[wbase + 704];
        FMA4(a2, q0, xv0); FMA4(a2, q1, xv1); FMA4(a2, q2, xv2); FMA4(a2, q3, xv3);
        q0 = wxlds4[wbase + 768]; q1 = wxlds4[wbase + 832];
        q2 = wxlds4[wbase + 896]; q3 = wxlds4[wbase + 960];
        FMA4(a3, q0, xv0); FMA4(a3, q1, xv1); FMA4(a3, q2, xv2); FMA4(a3, q3, xv3);
    }

    for (int s = 0; s < T_TOTAL; ++s) {
        const int sp = (s & 1) ^ 1;        // slot holding h_{s-1}
        const int sc = s & 1;              // slot receiving h_s

        // ---- per-wave autonomous poll: 16 tagged words -> registers ----
        const unsigned need = (unsigned)s;
        const unsigned long long* base = hdq + (size_t)sp * 1024 + pbase;
        unsigned long long v00, v01, v02, v03, v10, v11, v12, v13;
        unsigned long long v20, v21, v22, v23, v30, v31, v32, v33;
        bool dead = false;
        {
            int guard = 0;
            bool ok;
            do {
#define PLD(X, off) X = __hip_atomic_load(base + (off), __ATOMIC_RELAXED, \
                                          __HIP_MEMORY_SCOPE_AGENT)
                PLD(v00,   0); PLD(v01,   1); PLD(v02,   2); PLD(v03,   3);
                PLD(v10, 256); PLD(v11, 257); PLD(v12, 258); PLD(v13, 259);
                PLD(v20, 512); PLD(v21, 513); PLD(v22, 514); PLD(v23, 515);
                PLD(v30, 768); PLD(v31, 769); PLD(v32, 770); PLD(v33, 771);
#undef PLD
                ok = ((unsigned)(v00 >> 32) == need) & ((unsigned)(v01 >> 32) == need)
                   & ((unsigned)(v02 >> 32) == need) & ((unsigned)(v03 >> 32) == need)
                   & ((unsigned)(v10 >> 32) == need) & ((unsigned)(v11 >> 32) == need)
                   & ((unsigned)(v12 >> 32) == need) & ((unsigned)(v13 >> 32) == need)
                   & ((unsigned)(v20 >> 32) == need) & ((unsigned)(v21 >> 32) == need)
                   & ((unsigned)(v22 >> 32) == need) & ((unsigned)(v23 >> 32) == need)
                   & ((unsigned)(v30 >> 32) == need) & ((unsigned)(v31 >> 32) == need)
                   & ((unsigned)(v32 >> 32) == need) & ((unsigned)(v33 >> 32) == need);
                if (++guard >= (1 << 17)) { dead = true; break; }  // fast-fail
            } while (!__all(ok));
        }
        if (__any(dead)) break;            // wave-uniform bail: visible failure

        float4 h0 = make_float4(__uint_as_float((unsigned)v00),
                                __uint_as_float((unsigned)v01),
                                __uint_as_float((unsigned)v02),
                                __uint_as_float((unsigned)v03));
        float4 h1 = make_float4(__uint_as_float((unsigned)v10),
                                __uint_as_float((unsigned)v11),
                                __uint_as_float((unsigned)v12),
                                __uint_as_float((unsigned)v13));
        float4 h2 = make_float4(__uint_as_float((unsigned)v20),
                                __uint_as_float((unsigned)v21),
                                __uint_as_float((unsigned)v22),
                                __uint_as_float((unsigned)v23));
        float4 h3 = make_float4(__uint_as_float((unsigned)v30),
                                __uint_as_float((unsigned)v31),
                                __uint_as_float((unsigned)v32),
                                __uint_as_float((unsigned)v33));

        // ---- issue x_{s+1} loads (flight hides under the h-dot) ----
        const int snx = (s + 1 < T_TOTAL) ? s + 1 : s;
        const float4* xpn = (const float4*)(x + (size_t)snx * 512);
        float4 nx0 = xpn[seg], nx1 = xpn[seg + 32],
               nx2 = xpn[seg + 64], nx3 = xpn[seg + 96];

        // ---- h-dot on carried x-partials  [R8 layout, 0 conflicts] ----
        float4 w00 = whlds4[wbase +   0], w01 = whlds4[wbase +  64];
        float4 w02 = whlds4[wbase + 128], w03 = whlds4[wbase + 192];
        float4 w10 = whlds4[wbase + 256], w11 = whlds4[wbase + 320];
        float4 w12 = whlds4[wbase + 384], w13 = whlds4[wbase + 448];
        float4 w20 = whlds4[wbase + 512], w21 = whlds4[wbase + 576];
        float4 w22 = whlds4[wbase + 640], w23 = whlds4[wbase + 704];
        float4 w30 = whlds4[wbase + 768], w31 = whlds4[wbase + 832];
        float4 w32 = whlds4[wbase + 896], w33 = whlds4[wbase + 960];

        FMA4(a0, w00, h0); FMA4(a0, w01, h1); FMA4(a0, w02, h2); FMA4(a0, w03, h3);
        FMA4(a1, w10, h0); FMA4(a1, w11, h1); FMA4(a1, w12, h2); FMA4(a1, w13, h3);
        FMA4(a2, w20, h0); FMA4(a2, w21, h1); FMA4(a2, w22, h2); FMA4(a2, w23, h3);
        FMA4(a3, w30, h0); FMA4(a3, w31, h1); FMA4(a3, w32, h2); FMA4(a3, w33, h3);

        #pragma unroll
        for (int m = 1; m < 32; m <<= 1) {
            a0 += __shfl_xor(a0, m);
            a1 += __shfl_xor(a1, m);
            a2 += __shfl_xor(a2, m);
            a3 += __shfl_xor(a3, m);
        }

        // ---- 4-lane parallel activations ----
        float pre = (seg == 1) ? a1 + bias4.y
                  : (seg == 2) ? a2 + bias4.z
                  : (seg == 3) ? a3 + bias4.w
                  :              a0 + bias4.x;
        float act = (seg == 2) ? tanh_fast(pre) : sigm(pre);
        float ff  = __shfl(act, lbase);
        float iiv = __shfl(act, lbase + 1);
        float ccv = __shfl(act, lbase + 2);
        float ov  = __shfl(act, lbase + 3);

        if (seg == 0) {
            cold = fmaf(ff, cold, iiv * ccv);
            float hnew = tanh_fast(cold) * ov;
            unsigned long long tv = ((unsigned long long)(unsigned)(s + 1) << 32)
                                  | (unsigned long long)__float_as_uint(hnew);
            __hip_atomic_store(hdq + (size_t)sc * 1024 + b * 16 + r, tv,
                               __ATOMIC_RELAXED, __HIP_MEMORY_SCOPE_AGENT);
            if (s == T_TOTAL - 1) {
                out[row]       = cold;
                out[512 + row] = hnew;
            }
        }

        // ---- publish-flight window: x-partials for step s+1 ----
        float4 q0, q1, q2, q3;
        a0 = a1 = a2 = a3 = 0.f;
        q0 = wxlds4[wbase +   0]; q1 = wxlds4[wbase +  64];
        q2 = wxlds4[wbase + 128]; q3 = wxlds4[wbase + 192];
        FMA4(a0, q0, nx0); FMA4(a0, q1, nx1); FMA4(a0, q2, nx2); FMA4(a0, q3, nx3);
        q0 = wxlds4[wbase + 256]; q1 = wxlds4[wbase + 320];
        q2 = wxlds4[wbase + 384]; q3 = wxlds4[wbase + 448];
        FMA4(a1, q0, nx0); FMA4(a1, q1, nx1); FMA4(a1, q2, nx2); FMA4(a1, q3, nx3);
        q0 = wxlds4[wbase + 512]; q1 = wxlds4[wbase + 576];
        q2 = wxlds4[wbase + 640]; q3 = wxlds4[wbase + 704];
        FMA4(a2, q0, nx0); FMA4(a2, q1, nx1); FMA4(a2, q2, nx2); FMA4(a2, q3, nx3);
        q0 = wxlds4[wbase + 768]; q1 = wxlds4[wbase + 832];
        q2 = wxlds4[wbase + 896]; q3 = wxlds4[wbase + 960];
        FMA4(a3, q0, nx0); FMA4(a3, q1, nx1); FMA4(a3, q2, nx2); FMA4(a3, q3, nx3);
    }
}

// ---------------------------------------------------------------------------
extern "C" void kernel_launch(void* const* d_in, const int* in_sizes, int n_in,
                              void* d_out, int out_size, void* d_ws, size_t ws_size,
                              hipStream_t stream)
{
    const float* x  = (const float*)d_in[0];
    const float* wf = (const float*)d_in[1];
    const float* bf = (const float*)d_in[2];
    const float* wi = (const float*)d_in[3];
    const float* bi = (const float*)d_in[4];
    const float* wc = (const float*)d_in[5];
    const float* bc = (const float*)d_in[6];
    const float* wo = (const float*)d_in[7];
    const float* bo = (const float*)d_in[8];
    float* out = (float*)d_out;

    unsigned long long* hdq = (unsigned long long*)d_ws;     // 2*64*16*8 = 16384 B

    hipMemsetAsync(d_ws, 0, 16384, stream);   // tags=0 (s=0 poll passes), h=0

    lstm_fused<<<NBLK, 256, 0, stream>>>(x, wf, wi, wc, wo,
                                         bf, bi, bc, bo, hdq, out);
}

// Round 18
// 56270.538 us; speedup vs baseline: 2.0838x; 2.0838x over previous
//
#include <hip/hip_runtime.h>
#include <hip/hip_bf16.h>
#include <cstdint>

// LSTM, T=32768 steps, C=512, I=1024 (x 512 | h 512), fp32.
// R18 = R15 verbatim (best: 56.5k us, 1.72 us/step). R16/R17's barrier-free
// per-wave poll collapsed under 8x poll traffic (MALL congestion, like R5):
// detection must stay sparse (wave 0 only). R15's structure:
//   fused single launch; Wx+Wh in LDS (128 KB); pre-barrier = ONLY the poll;
//   x_{s+1} loads issued post-barrier (hide under h-dot); x-partials for s+1
//   computed in the publish-flight window; 4-lane parallel activations.
// Protocol: tagged u64 mailbox (tag<<32|bits), relaxed agent store publish,
// wave-0 batched 8-load poll. Remaining 1.72us/step = publish->visible MALL
// flight (~2.5-2.8k cyc incl. 64-block tail) + ~1 detect round + ~700 cyc
// critical-path compute -- the rendezvous latency floor (falsified levers:
// R6/R9/R11/R12/R13/R17).

#define T_TOTAL 32768
#define NBLK 64

__device__ __forceinline__ float sigm(float x) {
    return 1.0f / (1.0f + __expf(-x));
}
__device__ __forceinline__ float tanh_fast(float x) {
    float ax = fabsf(x);
    float e = __expf(2.0f * ax);          // +inf for large ax is fine -> t = 1
    float t = 1.0f - 2.0f / (e + 1.0f);
    return copysignf(t, x);
}

#define FMA4(a, wv, vv) \
    a = fmaf((wv).x, (vv).x, a); a = fmaf((wv).y, (vv).y, a); \
    a = fmaf((wv).z, (vv).z, a); a = fmaf((wv).w, (vv).w, a)

// ---------------------------------------------------------------------------
// 64 blocks x 256 threads, 1 block/CU. Block owns 8 rows.
// Thread map: tid = r*32 + seg (r=row 0..7, seg covers k in {4seg+128jj+e}).
// Weight LDS reader-keyed (lane-linear, 0 conflicts, R8-proven):
//   w?lds4[w*1024 + g*256 + jj*64 + lane], base col 0 (Wx) / 512 (Wh).
// Per step s:
//   [pre-barrier]  wave 0 polls 8 tagged words of h_{s-1} -> hl[sp]
//   [post-barrier] issue x_{s+1} loads; h-dot on carried x-partials; butterfly;
//                  4-lane parallel activations; seg==0 c/h update + ONE tagged
//                  relaxed agent store; then compute x-partials for s+1
//                  (hides under the remote publish flight).
// Slot-reuse induction identical to R6-R13 (per-word tags, parity slots).
// ---------------------------------------------------------------------------
__global__ __launch_bounds__(256, 1) void lstm_fused(
    const float* __restrict__ x,
    const float* __restrict__ wf, const float* __restrict__ wi,
    const float* __restrict__ wc, const float* __restrict__ wo,
    const float* __restrict__ bf, const float* __restrict__ bi,
    const float* __restrict__ bc, const float* __restrict__ bo,
    unsigned long long* __restrict__ hdq,   // [2][64][16] tagged h lines
    float* __restrict__ out)
{
    __shared__ alignas(16) float4 whlds4[4096];  // Wh slice, 64 KB
    __shared__ alignas(16) float4 wxlds4[4096];  // Wx slice, 64 KB
    __shared__ alignas(16) float  hl[2][512];    // parity-double-buffered h

    const int b   = blockIdx.x;            // 0..63
    const int tid = threadIdx.x;
    const int r   = tid >> 5;              // 0..7
    const int seg = tid & 31;              // 0..31
    const int w   = tid >> 6;              // wave 0..3
    const int l   = tid & 63;              // lane in wave

    // stage Wx AND Wh slices once (8192 float4s)
    #pragma unroll
    for (int k = 0; k < 32; ++k) {
        int idx  = k * 256 + tid;          // 0..8191
        int sel  = idx >> 12;              // 0: Wh, 1: Wx
        int idx2 = idx & 4095;
        int ll   = idx2 & 63;
        int jj   = (idx2 >> 6) & 3;
        int gg   = (idx2 >> 8) & 3;
        int ww   = idx2 >> 10;
        const float* Wp = (gg == 0) ? wf : (gg == 1) ? wi : (gg == 2) ? wc : wo;
        int row  = b * 8 + ww * 2 + (ll >> 5);
        int col  = 4 * (ll & 31) + 128 * jj + (sel ? 0 : 512);
        float4 v = *(const float4*)(Wp + (size_t)row * 1024 + col);
        if (sel) wxlds4[idx2] = v; else whlds4[idx2] = v;
    }
    const int row = b * 8 + r;
    float4 bias4 = make_float4(bf[row], bi[row], bc[row], bo[row]);

    float cold = 0.f;                      // c state in registers all T steps
    __syncthreads();

    const float4* hl4   = (const float4*)hl;
    const int     wbase = w * 1024 + l;    // + g*256 + jj*64
    const int     lbase = l & 32;          // base lane of this row-group in wave

    // ---- x-partials for step 0 (prologue) ----
    float a0, a1, a2, a3;
    {
        const float4* xp = (const float4*)x;   // step 0
        float4 xv0 = xp[seg], xv1 = xp[seg + 32],
               xv2 = xp[seg + 64], xv3 = xp[seg + 96];
        float4 q0, q1, q2, q3;
        a0 = a1 = a2 = a3 = 0.f;
        q0 = wxlds4[wbase +   0]; q1 = wxlds4[wbase +  64];
        q2 = wxlds4[wbase + 128]; q3 = wxlds4[wbase + 192];
        FMA4(a0, q0, xv0); FMA4(a0, q1, xv1); FMA4(a0, q2, xv2); FMA4(a0, q3, xv3);
        q0 = wxlds4[wbase + 256]; q1 = wxlds4[wbase + 320];
        q2 = wxlds4[wbase + 384]; q3 = wxlds4[wbase + 448];
        FMA4(a1, q0, xv0); FMA4(a1, q1, xv1); FMA4(a1, q2, xv2); FMA4(a1, q3, xv3);
        q0 = wxlds4[wbase + 512]; q1 = wxlds4[wbase + 576];
        q2 = wxlds4[wbase + 640]; q3 = wxlds4[wbase + 704];
        FMA4(a2, q0, xv0); FMA4(a2, q1, xv1); FMA4(a2, q2, xv2); FMA4(a2, q3, xv3);
        q0 = wxlds4[wbase + 768]; q1 = wxlds4[wbase + 832];
        q2 = wxlds4[wbase + 896]; q3 = wxlds4[wbase + 960];
        FMA4(a3, q0, xv0); FMA4(a3, q1, xv1); FMA4(a3, q2, xv2); FMA4(a3, q3, xv3);
    }

    for (int s = 0; s < T_TOTAL; ++s) {
        const int sp = (s & 1) ^ 1;        // slot holding h_{s-1}
        const int sc = s & 1;              // slot receiving h_s

        // ---- pre-barrier: ONLY the poll (wave 0) ----
        if (tid < 64) {
            const unsigned need = (unsigned)s;
            const unsigned long long* src =
                hdq + (size_t)sp * 1024 + (tid >> 3) * 16 + (tid & 7);
            unsigned long long v0, v1, v2, v3, v4, v5, v6, v7;
            int guard = 0;
            bool ok = false;
            do {
                v0 = __hip_atomic_load(src,       __ATOMIC_RELAXED, __HIP_MEMORY_SCOPE_AGENT);
                v1 = __hip_atomic_load(src + 128, __ATOMIC_RELAXED, __HIP_MEMORY_SCOPE_AGENT);
                v2 = __hip_atomic_load(src + 256, __ATOMIC_RELAXED, __HIP_MEMORY_SCOPE_AGENT);
                v3 = __hip_atomic_load(src + 384, __ATOMIC_RELAXED, __HIP_MEMORY_SCOPE_AGENT);
                v4 = __hip_atomic_load(src + 512, __ATOMIC_RELAXED, __HIP_MEMORY_SCOPE_AGENT);
                v5 = __hip_atomic_load(src + 640, __ATOMIC_RELAXED, __HIP_MEMORY_SCOPE_AGENT);
                v6 = __hip_atomic_load(src + 768, __ATOMIC_RELAXED, __HIP_MEMORY_SCOPE_AGENT);
                v7 = __hip_atomic_load(src + 896, __ATOMIC_RELAXED, __HIP_MEMORY_SCOPE_AGENT);
                ok = ((unsigned)(v0 >> 32) == need) & ((unsigned)(v1 >> 32) == need)
                   & ((unsigned)(v2 >> 32) == need) & ((unsigned)(v3 >> 32) == need)
                   & ((unsigned)(v4 >> 32) == need) & ((unsigned)(v5 >> 32) == need)
                   & ((unsigned)(v6 >> 32) == need) & ((unsigned)(v7 >> 32) == need);
            } while (!ok && ++guard < (1 << 20));
            hl[sp][tid]       = __uint_as_float((unsigned)v0);
            hl[sp][tid + 64]  = __uint_as_float((unsigned)v1);
            hl[sp][tid + 128] = __uint_as_float((unsigned)v2);
            hl[sp][tid + 192] = __uint_as_float((unsigned)v3);
            hl[sp][tid + 256] = __uint_as_float((unsigned)v4);
            hl[sp][tid + 320] = __uint_as_float((unsigned)v5);
            hl[sp][tid + 384] = __uint_as_float((unsigned)v6);
            hl[sp][tid + 448] = __uint_as_float((unsigned)v7);
        }
        __syncthreads();

        // ---- issue x_{s+1} loads early (flight hides under the h-dot) ----
        const int snx = (s + 1 < T_TOTAL) ? s + 1 : s;   // clamp: harmless redo
        const float4* xpn = (const float4*)(x + (size_t)snx * 512);
        float4 nx0 = xpn[seg], nx1 = xpn[seg + 32],
               nx2 = xpn[seg + 64], nx3 = xpn[seg + 96];

        // ---- h-dot on carried x-partials  [R8 layout, 0 conflicts] ----
        float4 h0 = hl4[sp * 128 + seg];
        float4 h1 = hl4[sp * 128 + seg + 32];
        float4 h2 = hl4[sp * 128 + seg + 64];
        float4 h3 = hl4[sp * 128 + seg + 96];

        float4 w00 = whlds4[wbase +   0], w01 = whlds4[wbase +  64];
        float4 w02 = whlds4[wbase + 128], w03 = whlds4[wbase + 192];
        float4 w10 = whlds4[wbase + 256], w11 = whlds4[wbase + 320];
        float4 w12 = whlds4[wbase + 384], w13 = whlds4[wbase + 448];
        float4 w20 = whlds4[wbase + 512], w21 = whlds4[wbase + 576];
        float4 w22 = whlds4[wbase + 640], w23 = whlds4[wbase + 704];
        float4 w30 = whlds4[wbase + 768], w31 = whlds4[wbase + 832];
        float4 w32 = whlds4[wbase + 896], w33 = whlds4[wbase + 960];

        FMA4(a0, w00, h0); FMA4(a0, w01, h1); FMA4(a0, w02, h2); FMA4(a0, w03, h3);
        FMA4(a1, w10, h0); FMA4(a1, w11, h1); FMA4(a1, w12, h2); FMA4(a1, w13, h3);
        FMA4(a2, w20, h0); FMA4(a2, w21, h1); FMA4(a2, w22, h2); FMA4(a2, w23, h3);
        FMA4(a3, w30, h0); FMA4(a3, w31, h1); FMA4(a3, w32, h2); FMA4(a3, w33, h3);

        #pragma unroll
        for (int m = 1; m < 32; m <<= 1) {
            a0 += __shfl_xor(a0, m);
            a1 += __shfl_xor(a1, m);
            a2 += __shfl_xor(a2, m);
            a3 += __shfl_xor(a3, m);
        }

        // ---- 4-lane parallel activations (one transcendental chain) ----
        float pre = (seg == 1) ? a1 + bias4.y
                  : (seg == 2) ? a2 + bias4.z
                  : (seg == 3) ? a3 + bias4.w
                  :              a0 + bias4.x;
        float act = (seg == 2) ? tanh_fast(pre) : sigm(pre);
        float ff  = __shfl(act, lbase);
        float iiv = __shfl(act, lbase + 1);
        float ccv = __shfl(act, lbase + 2);
        float ov  = __shfl(act, lbase + 3);

        if (seg == 0) {
            cold = fmaf(ff, cold, iiv * ccv);
            float hnew = tanh_fast(cold) * ov;
            unsigned long long tv = ((unsigned long long)(unsigned)(s + 1) << 32)
                                  | (unsigned long long)__float_as_uint(hnew);
            __hip_atomic_store(hdq + (size_t)sc * 1024 + b * 16 + r, tv,
                               __ATOMIC_RELAXED, __HIP_MEMORY_SCOPE_AGENT);
            if (s == T_TOTAL - 1) {
                out[row]       = cold;
                out[512 + row] = hnew;
            }
        }

        // ---- publish-flight window: x-partials for step s+1 ----
        float4 q0, q1, q2, q3;
        a0 = a1 = a2 = a3 = 0.f;
        q0 = wxlds4[wbase +   0]; q1 = wxlds4[wbase +  64];
        q2 = wxlds4[wbase + 128]; q3 = wxlds4[wbase + 192];
        FMA4(a0, q0, nx0); FMA4(a0, q1, nx1); FMA4(a0, q2, nx2); FMA4(a0, q3, nx3);
        q0 = wxlds4[wbase + 256]; q1 = wxlds4[wbase + 320];
        q2 = wxlds4[wbase + 384]; q3 = wxlds4[wbase + 448];
        FMA4(a1, q0, nx0); FMA4(a1, q1, nx1); FMA4(a1, q2, nx2); FMA4(a1, q3, nx3);
        q0 = wxlds4[wbase + 512]; q1 = wxlds4[wbase + 576];
        q2 = wxlds4[wbase + 640]; q3 = wxlds4[wbase + 704];
        FMA4(a2, q0, nx0); FMA4(a2, q1, nx1); FMA4(a2, q2, nx2); FMA4(a2, q3, nx3);
        q0 = wxlds4[wbase + 768]; q1 = wxlds4[wbase + 832];
        q2 = wxlds4[wbase + 896]; q3 = wxlds4[wbase + 960];
        FMA4(a3, q0, nx0); FMA4(a3, q1, nx1); FMA4(a3, q2, nx2); FMA4(a3, q3, nx3);
    }
}

// ---------------------------------------------------------------------------
extern "C" void kernel_launch(void* const* d_in, const int* in_sizes, int n_in,
                              void* d_out, int out_size, void* d_ws, size_t ws_size,
                              hipStream_t stream)
{
    const float* x  = (const float*)d_in[0];
    const float* wf = (const float*)d_in[1];
    const float* bf = (const float*)d_in[2];
    const float* wi = (const float*)d_in[3];
    const float* bi = (const float*)d_in[4];
    const float* wc = (const float*)d_in[5];
    const float* bc = (const float*)d_in[6];
    const float* wo = (const float*)d_in[7];
    const float* bo = (const float*)d_in[8];
    float* out = (float*)d_out;

    unsigned long long* hdq = (unsigned long long*)d_ws;     // 2*64*16*8 = 16384 B

    hipMemsetAsync(d_ws, 0, 16384, stream);   // tags=0 (s=0 poll passes), h=0

    lstm_fused<<<NBLK, 256, 0, stream>>>(x, wf, wi, wc, wo,
                                         bf, bi, bc, bo, hdq, out);
}